// Round 1
// baseline (100.210 us; speedup 1.0000x reference)
//
#include <hip/hip_runtime.h>

// AttentionBasedPooling: B=2048, F=32 (P=496 pairs), D=64, H=64.
// afm[b] = sum_p attn[b,p] * dot(x_i_p, x_j_p), attn = softmax over p of
// scores[p] = relu((x_i*x_j) @ W1 + b1) @ Ws + bs.
// One block per batch element; MFMA 16x16x32 bf16 for the [496x64]@[64x64] MLP.

#define F 32
#define D 64
#define H 64
#define P 496   // F*(F-1)/2
#define NT 4    // n-tiles of 16 over H=64
#define MT 31   // m-tiles of 16 over P=496
#define XPAD 68 // 64 + 4: breaks 32-bank aliasing, keeps 16B alignment

typedef __attribute__((ext_vector_type(8))) short bf16x8;
typedef __attribute__((ext_vector_type(4))) float f32x4;

__device__ inline short f2bf(float f) {
    union { float f; unsigned u; } v; v.f = f;
    unsigned r = v.u + 0x7FFFu + ((v.u >> 16) & 1u);  // RNE
    return (short)(r >> 16);
}

__global__ __launch_bounds__(256) void afm_kernel(
    const float* __restrict__ x, const float* __restrict__ W1,
    const float* __restrict__ b1, const float* __restrict__ Ws,
    const float* __restrict__ bs, float* __restrict__ out)
{
    __shared__ float xs[F][XPAD];
    __shared__ short iis[512], jjs[512];
    __shared__ float scores[512];
    __shared__ float svals[512];
    __shared__ float b1s[H], wss[H];
    __shared__ float redmax[4], rednum[4], redden[4];

    const int tid  = threadIdx.x;
    const int b    = blockIdx.x;
    const int lane = tid & 63;
    const int wid  = tid >> 6;
    const int l15  = lane & 15;
    const int quad = lane >> 4;

    // ---- stage x[b] (coalesced; 2-way bank alias on write = free) ----
    const float* xb = x + (size_t)b * (F * D);
    for (int idx = tid; idx < F * D; idx += 256)
        xs[idx >> 6][idx & 63] = xb[idx];
    if (tid < H) { b1s[tid] = b1[tid]; wss[tid] = Ws[tid]; }
    // pair table (np.triu_indices(F, k=1) row-major order)
    for (int p = tid; p < P; p += 256) {
        int i = 0, rem = p;
        while (rem >= F - 1 - i) { rem -= F - 1 - i; ++i; }
        iis[p] = (short)i; jjs[p] = (short)(i + 1 + rem);
    }
    const float bsv = bs[0];
    __syncthreads();

    // ---- W1 as B-fragments in registers (once per wave; L1/L2-cached) ----
    // B layout: B[k = quad*8 + j (+32*ks)][n = nt*16 + l15]
    bf16x8 bfrag[NT][2];
    #pragma unroll
    for (int nt = 0; nt < NT; ++nt)
        #pragma unroll
        for (int ks = 0; ks < 2; ++ks)
            #pragma unroll
            for (int j8 = 0; j8 < 8; ++j8) {
                int k = quad * 8 + j8 + ks * 32;
                int n = nt * 16 + l15;
                bfrag[nt][ks][j8] = f2bf(W1[k * H + n]);
            }

    // ---- per-wave m-tiles: 16 pairs each, 31 tiles round-robin ----
    for (int t = wid; t < MT; t += 4) {
        const int p0 = t * 16;
        const int p  = p0 + l15;
        const int ip = iis[p], jp = jjs[p];

        bf16x8 afrag[2];
        float ssum = 0.f;
        #pragma unroll
        for (int ks = 0; ks < 2; ++ks) {
            const int kb = quad * 8 + ks * 32;
            float4 xi0 = *(const float4*)&xs[ip][kb];
            float4 xi1 = *(const float4*)&xs[ip][kb + 4];
            float4 xj0 = *(const float4*)&xs[jp][kb];
            float4 xj1 = *(const float4*)&xs[jp][kb + 4];
            float c[8];
            c[0] = xi0.x * xj0.x; c[1] = xi0.y * xj0.y;
            c[2] = xi0.z * xj0.z; c[3] = xi0.w * xj0.w;
            c[4] = xi1.x * xj1.x; c[5] = xi1.y * xj1.y;
            c[6] = xi1.z * xj1.z; c[7] = xi1.w * xj1.w;
            #pragma unroll
            for (int j8 = 0; j8 < 8; ++j8) {
                ssum += c[j8];
                afrag[ks][j8] = f2bf(c[j8]);
            }
        }
        // s_p = dot(x_i, x_j) in fp32: reduce partial (16 k's) across quads
        ssum += __shfl_xor(ssum, 16, 64);
        ssum += __shfl_xor(ssum, 32, 64);
        if (quad == 0) svals[p] = ssum;

        f32x4 acc[NT];
        #pragma unroll
        for (int nt = 0; nt < NT; ++nt) { f32x4 z = {0.f,0.f,0.f,0.f}; acc[nt] = z; }
        #pragma unroll
        for (int ks = 0; ks < 2; ++ks)
            #pragma unroll
            for (int nt = 0; nt < NT; ++nt)
                acc[nt] = __builtin_amdgcn_mfma_f32_16x16x32_bf16(
                              afrag[ks], bfrag[nt][ks], acc[nt], 0, 0, 0);

        // epilogue: score[m] = sum_n relu(C[m][n]+b1[n])*Ws[n]
        // C layout: row m = quad*4+reg, col n = nt*16+l15
        float sp[4] = {0.f, 0.f, 0.f, 0.f};
        #pragma unroll
        for (int nt = 0; nt < NT; ++nt) {
            const int n = nt * 16 + l15;
            const float bb = b1s[n], ww = wss[n];
            #pragma unroll
            for (int reg = 0; reg < 4; ++reg) {
                float v = acc[nt][reg] + bb;
                v = v > 0.f ? v : 0.f;
                sp[reg] += v * ww;
            }
        }
        #pragma unroll
        for (int reg = 0; reg < 4; ++reg) {
            float s = sp[reg];
            s += __shfl_xor(s, 1, 64);
            s += __shfl_xor(s, 2, 64);
            s += __shfl_xor(s, 4, 64);
            s += __shfl_xor(s, 8, 64);
            if (l15 == 0) scores[p0 + quad * 4 + reg] = s + bsv;
        }
    }
    __syncthreads();

    // ---- softmax over 496 pairs, weighted sum of s_p ----
    float m = -1e30f;
    for (int p = tid; p < P; p += 256) m = fmaxf(m, scores[p]);
    #pragma unroll
    for (int off = 32; off >= 1; off >>= 1) m = fmaxf(m, __shfl_xor(m, off, 64));
    if (lane == 0) redmax[wid] = m;
    __syncthreads();
    m = fmaxf(fmaxf(redmax[0], redmax[1]), fmaxf(redmax[2], redmax[3]));

    float num = 0.f, den = 0.f;
    for (int p = tid; p < P; p += 256) {
        float e = __expf(scores[p] - m);
        num += e * svals[p];
        den += e;
    }
    #pragma unroll
    for (int off = 32; off >= 1; off >>= 1) {
        num += __shfl_xor(num, off, 64);
        den += __shfl_xor(den, off, 64);
    }
    if (lane == 0) { rednum[wid] = num; redden[wid] = den; }
    __syncthreads();
    if (tid == 0) {
        float nn = rednum[0] + rednum[1] + rednum[2] + rednum[3];
        float dd = redden[0] + redden[1] + redden[2] + redden[3];
        out[b] = nn / dd;
    }
}

extern "C" void kernel_launch(void* const* d_in, const int* in_sizes, int n_in,
                              void* d_out, int out_size, void* d_ws, size_t ws_size,
                              hipStream_t stream) {
    const float* x  = (const float*)d_in[0];
    const float* W1 = (const float*)d_in[1];
    const float* b1 = (const float*)d_in[2];
    const float* Ws = (const float*)d_in[3];
    const float* bs = (const float*)d_in[4];
    float* out = (float*)d_out;
    const int B = in_sizes[0] / (F * D);  // 2048
    afm_kernel<<<B, 256, 0, stream>>>(x, W1, b1, Ws, bs, out);
}

// Round 2
// 94.794 us; speedup vs baseline: 1.0571x; 1.0571x over previous
//
#include <hip/hip_runtime.h>

// AttentionBasedPooling: B=2048, F=32 (P=496 pairs), D=64, H=64.
// afm[b] = sum_p attn[b,p] * dot(x_i,x_j); attn = softmax_p of
// scores[p] = relu((x_i*x_j)@W1 + b1)@Ws + bs.
// One block/batch. MFMA 16x16x32 bf16. x staged in LDS as bf16 (RNE).
// s_p extracted via an extra MFMA with an all-ones column-0 B fragment.
// All per-tile reductions on the VALU (DPP), not the DS pipe.

#define F 32
#define D 64
#define H 64
#define P 496
#define NT 4
#define MT 31
#define RB 72   // shorts per xs row: 64 + 8 pad -> 144 B row stride (16B-aligned, 4-bank skew)

typedef __attribute__((ext_vector_type(8))) short bf16x8;
typedef __attribute__((ext_vector_type(4))) float f32x4;

__device__ inline unsigned rne_hi(float f) {
    unsigned u = __float_as_uint(f);
    return u + 0x7FFFu + ((u >> 16) & 1u);   // bf16 bits land in [31:16]
}
// pack two floats -> 2x bf16 (RNE); a -> low short, b -> high short
__device__ inline int pack_rne(float a, float b) {
    return (int)__builtin_amdgcn_perm(rne_hi(b), rne_hi(a), 0x07060302u);
}
// product of two bf16 pairs (packed in ints), repacked to bf16 pair
__device__ inline int prodpk(int ri, int rj) {
    float a0 = __int_as_float(ri << 16);
    float a1 = __int_as_float(ri & 0xFFFF0000);
    float b0 = __int_as_float(rj << 16);
    float b1 = __int_as_float(rj & 0xFFFF0000);
    return pack_rne(a0 * b0, a1 * b1);
}

// VALU-pipe butterfly add over the 16-lane row (no DS traffic)
#define DPP_ADD(v, ctrl) ((v) + __int_as_float(__builtin_amdgcn_update_dpp( \
        0, __float_as_int(v), (ctrl), 0xF, 0xF, true)))

__global__ __launch_bounds__(256, 4) void afm_kernel(
    const float* __restrict__ x, const float* __restrict__ W1,
    const float* __restrict__ b1, const float* __restrict__ Ws,
    const float* __restrict__ bs, float* __restrict__ out)
{
    __shared__ short xs[F * RB];          // bf16 x-tile
    __shared__ int   pairtab[512];        // (i_off<<16)|j_off byte offsets
    __shared__ float scores[512];
    __shared__ float svals[512];
    __shared__ float2 bw[H];              // {b1[n], Ws[n]}
    __shared__ float redmax[4], rednum[4], redden[4];

    const int tid  = threadIdx.x;
    const int b    = blockIdx.x;
    const int lane = tid & 63;
    const int wid  = tid >> 6;
    const int l15  = lane & 15;
    const int quad = lane >> 4;

    // ---- stage x[b] -> bf16 LDS (coalesced float4 reads, RNE convert) ----
    const float4* xb4 = (const float4*)(x + (size_t)b * (F * D));
    for (int v = tid; v < (F * D) / 4; v += 256) {
        float4 w = xb4[v];
        int row = v >> 4, col = (v & 15) * 4;
        int lo = pack_rne(w.x, w.y), hi = pack_rne(w.z, w.w);
        *(int2*)&xs[row * RB + col] = make_int2(lo, hi);
    }
    if (tid < H) bw[tid] = make_float2(b1[tid], Ws[tid]);
    for (int p = tid; p < P; p += 256) {   // triu_indices(F,1) row-major
        int i = 0, rem = p;
        while (rem >= F - 1 - i) { rem -= F - 1 - i; ++i; }
        int j = i + 1 + rem;
        pairtab[p] = (i * RB * 2) << 16 | (j * RB * 2);
    }
    const float bsv = bs[0];
    __syncthreads();

    // ---- W1 as B-fragments in registers (B[k=quad*8+j+32ks][n=nt*16+l15]) ----
    bf16x8 bfrag[NT][2];
    #pragma unroll
    for (int nt = 0; nt < NT; ++nt)
        #pragma unroll
        for (int ks = 0; ks < 2; ++ks)
            #pragma unroll
            for (int j8 = 0; j8 < 8; ++j8) {
                int k = quad * 8 + j8 + ks * 32;
                unsigned u = rne_hi(W1[k * H + nt * 16 + l15]);
                bfrag[nt][ks][j8] = (short)(u >> 16);
            }
    // all-ones column-0 B fragment: C[:,0] = row-sum of A = s_p
    const short onev = (l15 == 0) ? (short)0x3F80 : (short)0;
    const bf16x8 onesf = {onev, onev, onev, onev, onev, onev, onev, onev};

    float bb[NT], ww[NT];
    #pragma unroll
    for (int nt = 0; nt < NT; ++nt) {
        float2 t = bw[nt * 16 + l15];
        bb[nt] = t.x; ww[nt] = t.y;
    }

    const char* xsb = (const char*)xs;

    // ---- per-wave m-tiles of 16 pairs ----
    for (int t = wid; t < MT; t += 4) {
        const int p0 = t * 16;
        const int pk = pairtab[p0 + l15];
        const int io = ((unsigned)pk) >> 16;
        const int jo = pk & 0xFFFF;
        const int qb = quad << 4;

        int4 xi0 = *(const int4*)(xsb + io + qb);        // k 0..31 slice
        int4 xj0 = *(const int4*)(xsb + jo + qb);
        int4 xi1 = *(const int4*)(xsb + io + 64 + qb);   // k 32..63 slice
        int4 xj1 = *(const int4*)(xsb + jo + 64 + qb);

        union { int i[4]; bf16x8 v; } A0, A1;
        A0.i[0] = prodpk(xi0.x, xj0.x); A0.i[1] = prodpk(xi0.y, xj0.y);
        A0.i[2] = prodpk(xi0.z, xj0.z); A0.i[3] = prodpk(xi0.w, xj0.w);
        A1.i[0] = prodpk(xi1.x, xj1.x); A1.i[1] = prodpk(xi1.y, xj1.y);
        A1.i[2] = prodpk(xi1.z, xj1.z); A1.i[3] = prodpk(xi1.w, xj1.w);

        f32x4 acc[NT];
        #pragma unroll
        for (int nt = 0; nt < NT; ++nt) { f32x4 z = {0.f,0.f,0.f,0.f}; acc[nt] = z; }
        f32x4 accs = {0.f, 0.f, 0.f, 0.f};

        #pragma unroll
        for (int nt = 0; nt < NT; ++nt)
            acc[nt] = __builtin_amdgcn_mfma_f32_16x16x32_bf16(A0.v, bfrag[nt][0], acc[nt], 0, 0, 0);
        accs = __builtin_amdgcn_mfma_f32_16x16x32_bf16(A0.v, onesf, accs, 0, 0, 0);
        #pragma unroll
        for (int nt = 0; nt < NT; ++nt)
            acc[nt] = __builtin_amdgcn_mfma_f32_16x16x32_bf16(A1.v, bfrag[nt][1], acc[nt], 0, 0, 0);
        accs = __builtin_amdgcn_mfma_f32_16x16x32_bf16(A1.v, onesf, accs, 0, 0, 0);

        // score[m] = sum_n relu(C[m][n]+b1[n])*Ws[n];  C: row=quad*4+reg, col=nt*16+l15
        float spr[4];
        #pragma unroll
        for (int reg = 0; reg < 4; ++reg) {
            float s = 0.f;
            #pragma unroll
            for (int nt = 0; nt < NT; ++nt) {
                float v = acc[nt][reg] + bb[nt];
                v = v > 0.f ? v : 0.f;
                s += v * ww[nt];
            }
            s = DPP_ADD(s, 0xB1);   // xor1 (quad_perm 1,0,3,2)
            s = DPP_ADD(s, 0x4E);   // xor2 (quad_perm 2,3,0,1)
            s = DPP_ADD(s, 0x141);  // row_half_mirror (crosses 4-groups in 8)
            s = DPP_ADD(s, 0x140);  // row_mirror (crosses 8-halves in 16)
            spr[reg] = s;
        }
        if (l15 == 0) {
            *(float4*)&svals[p0 + quad * 4] =
                make_float4(accs[0], accs[1], accs[2], accs[3]);
            *(float4*)&scores[p0 + quad * 4] =
                make_float4(spr[0] + bsv, spr[1] + bsv, spr[2] + bsv, spr[3] + bsv);
        }
    }
    __syncthreads();

    // ---- softmax over 496 pairs; afm = sum attn*s ----
    float m = -1e30f;
    for (int p = tid; p < P; p += 256) m = fmaxf(m, scores[p]);
    #pragma unroll
    for (int off = 32; off >= 1; off >>= 1) m = fmaxf(m, __shfl_xor(m, off, 64));
    if (lane == 0) redmax[wid] = m;
    __syncthreads();
    m = fmaxf(fmaxf(redmax[0], redmax[1]), fmaxf(redmax[2], redmax[3]));

    float num = 0.f, den = 0.f;
    for (int p = tid; p < P; p += 256) {
        float e = __expf(scores[p] - m);
        num += e * svals[p];
        den += e;
    }
    #pragma unroll
    for (int off = 32; off >= 1; off >>= 1) {
        num += __shfl_xor(num, off, 64);
        den += __shfl_xor(den, off, 64);
    }
    if (lane == 0) { rednum[wid] = num; redden[wid] = den; }
    __syncthreads();
    if (tid == 0) {
        float nn = rednum[0] + rednum[1] + rednum[2] + rednum[3];
        float dd = redden[0] + redden[1] + redden[2] + redden[3];
        out[b] = nn / dd;
    }
}

extern "C" void kernel_launch(void* const* d_in, const int* in_sizes, int n_in,
                              void* d_out, int out_size, void* d_ws, size_t ws_size,
                              hipStream_t stream) {
    const float* x  = (const float*)d_in[0];
    const float* W1 = (const float*)d_in[1];
    const float* b1 = (const float*)d_in[2];
    const float* Ws = (const float*)d_in[3];
    const float* bs = (const float*)d_in[4];
    float* out = (float*)d_out;
    const int B = in_sizes[0] / (F * D);  // 2048
    afm_kernel<<<B, 256, 0, stream>>>(x, W1, b1, Ws, bs, out);
}

// Round 3
// 84.963 us; speedup vs baseline: 1.1795x; 1.1157x over previous
//
#include <hip/hip_runtime.h>

// AttentionBasedPooling: B=2048, F=32 (P=496 pairs), D=64, H=64.
// afm[b] = sum_p attn[b,p] * dot(x_i,x_j); attn = softmax_p of
// scores[p] = relu((x_i*x_j)@W1 + b1)@Ws + bs.
// One block/batch. FP16 datapath: x staged in LDS as f16 (RNE); cross
// products via v_pk_mul_f16 (1 instr / 2 products); mfma_f32_16x16x32_f16.
// s_p = dot(x_i,x_j) via an extra MFMA against an all-ones column-0 B frag.
// Per-tile reductions on the VALU (DPP), keeping the DS pipe for tile loads.

#define F 32
#define D 64
#define H 64
#define P 496
#define NT 4
#define MT 31
#define RB 72   // f16 per xs row: 64 + 8 pad -> 144 B row stride (16B-aligned, 4-bank skew)

typedef __attribute__((ext_vector_type(8))) _Float16 f16x8;
typedef __attribute__((ext_vector_type(2))) _Float16 f16x2;
typedef __attribute__((ext_vector_type(4))) float f32x4;

// VALU-pipe butterfly add over the 16-lane row (no DS traffic)
#define DPP_ADD(v, ctrl) ((v) + __int_as_float(__builtin_amdgcn_update_dpp( \
        0, __float_as_int(v), (ctrl), 0xF, 0xF, true)))

__global__ __launch_bounds__(256, 4) void afm_kernel(
    const float* __restrict__ x, const float* __restrict__ W1,
    const float* __restrict__ b1, const float* __restrict__ Ws,
    const float* __restrict__ bs, float* __restrict__ out)
{
    __shared__ _Float16 xs[F * RB];       // f16 x-tile
    __shared__ int   pairtab[512];        // (i_off<<16)|j_off byte offsets
    __shared__ float scores[512];
    __shared__ float svals[512];
    __shared__ float2 bw[H];              // {b1[n], Ws[n]}
    __shared__ float redmax[4], rednum[4], redden[4];

    const int tid  = threadIdx.x;
    const int b    = blockIdx.x;
    const int lane = tid & 63;
    const int wid  = tid >> 6;
    const int l15  = lane & 15;
    const int quad = lane >> 4;

    // ---- stage x[b] -> f16 LDS (coalesced float4 reads, RNE convert) ----
    const float4* xb4 = (const float4*)(x + (size_t)b * (F * D));
    for (int v = tid; v < (F * D) / 4; v += 256) {
        float4 w = xb4[v];
        int row = v >> 4, col = (v & 15) * 4;
        f16x2 lo = { (_Float16)w.x, (_Float16)w.y };
        f16x2 hi = { (_Float16)w.z, (_Float16)w.w };
        *(f16x2*)&xs[row * RB + col]     = lo;
        *(f16x2*)&xs[row * RB + col + 2] = hi;
    }
    if (tid < H) bw[tid] = make_float2(b1[tid], Ws[tid]);
    for (int p = tid; p < P; p += 256) {   // triu_indices(F,1) row-major
        int i = 0, rem = p;
        while (rem >= F - 1 - i) { rem -= F - 1 - i; ++i; }
        int j = i + 1 + rem;
        pairtab[p] = (i * RB * 2) << 16 | (j * RB * 2);
    }
    const float bsv = bs[0];
    __syncthreads();

    // ---- W1 as B-fragments in registers (B[k=quad*8+j+32ks][n=nt*16+l15]) ----
    f16x8 bfrag[NT][2];
    #pragma unroll
    for (int nt = 0; nt < NT; ++nt)
        #pragma unroll
        for (int ks = 0; ks < 2; ++ks)
            #pragma unroll
            for (int j8 = 0; j8 < 8; ++j8) {
                int k = quad * 8 + j8 + ks * 32;
                bfrag[nt][ks][j8] = (_Float16)W1[k * H + nt * 16 + l15];
            }
    // all-ones column-0 B fragment: C[:,0] = row-sum of A = s_p
    const _Float16 onev = (l15 == 0) ? (_Float16)1.0f : (_Float16)0.0f;
    const f16x8 onesf = {onev, onev, onev, onev, onev, onev, onev, onev};

    float bb[NT], ww[NT];
    #pragma unroll
    for (int nt = 0; nt < NT; ++nt) {
        float2 t = bw[nt * 16 + l15];
        bb[nt] = t.x; ww[nt] = t.y;
    }

    const char* xsb = (const char*)xs;

    // ---- per-wave m-tiles of 16 pairs ----
    for (int t = wid; t < MT; t += 4) {
        const int p0 = t * 16;
        const int pk = pairtab[p0 + l15];
        const int io = ((unsigned)pk) >> 16;
        const int jo = pk & 0xFFFF;
        const int qb = quad << 4;

        f16x8 xi0 = *(const f16x8*)(xsb + io + qb);        // k 0..31 slice
        f16x8 xj0 = *(const f16x8*)(xsb + jo + qb);
        f16x8 xi1 = *(const f16x8*)(xsb + io + 64 + qb);   // k 32..63 slice
        f16x8 xj1 = *(const f16x8*)(xsb + jo + 64 + qb);

        f16x8 A0 = xi0 * xj0;   // 4x v_pk_mul_f16
        f16x8 A1 = xi1 * xj1;

        f32x4 acc[NT];
        #pragma unroll
        for (int nt = 0; nt < NT; ++nt) { f32x4 z = {0.f,0.f,0.f,0.f}; acc[nt] = z; }
        f32x4 accs = {0.f, 0.f, 0.f, 0.f};

        #pragma unroll
        for (int nt = 0; nt < NT; ++nt)
            acc[nt] = __builtin_amdgcn_mfma_f32_16x16x32_f16(A0, bfrag[nt][0], acc[nt], 0, 0, 0);
        accs = __builtin_amdgcn_mfma_f32_16x16x32_f16(A0, onesf, accs, 0, 0, 0);
        #pragma unroll
        for (int nt = 0; nt < NT; ++nt)
            acc[nt] = __builtin_amdgcn_mfma_f32_16x16x32_f16(A1, bfrag[nt][1], acc[nt], 0, 0, 0);
        accs = __builtin_amdgcn_mfma_f32_16x16x32_f16(A1, onesf, accs, 0, 0, 0);

        // score[m] = sum_n relu(C[m][n]+b1[n])*Ws[n];  C: row=quad*4+reg, col=nt*16+l15
        float spr[4];
        #pragma unroll
        for (int reg = 0; reg < 4; ++reg) {
            float s = 0.f;
            #pragma unroll
            for (int nt = 0; nt < NT; ++nt) {
                float v = acc[nt][reg] + bb[nt];
                v = v > 0.f ? v : 0.f;
                s += v * ww[nt];
            }
            s = DPP_ADD(s, 0xB1);   // xor1 (quad_perm 1,0,3,2)
            s = DPP_ADD(s, 0x4E);   // xor2 (quad_perm 2,3,0,1)
            s = DPP_ADD(s, 0x141);  // row_half_mirror
            s = DPP_ADD(s, 0x140);  // row_mirror
            spr[reg] = s;
        }
        if (l15 == 0) {
            *(float4*)&svals[p0 + quad * 4] =
                make_float4(accs[0], accs[1], accs[2], accs[3]);
            *(float4*)&scores[p0 + quad * 4] =
                make_float4(spr[0] + bsv, spr[1] + bsv, spr[2] + bsv, spr[3] + bsv);
        }
    }
    __syncthreads();

    // ---- softmax over 496 pairs; afm = sum attn*s ----
    float m = -1e30f;
    for (int p = tid; p < P; p += 256) m = fmaxf(m, scores[p]);
    #pragma unroll
    for (int off = 32; off >= 1; off >>= 1) m = fmaxf(m, __shfl_xor(m, off, 64));
    if (lane == 0) redmax[wid] = m;
    __syncthreads();
    m = fmaxf(fmaxf(redmax[0], redmax[1]), fmaxf(redmax[2], redmax[3]));

    float num = 0.f, den = 0.f;
    for (int p = tid; p < P; p += 256) {
        float e = __expf(scores[p] - m);
        num += e * svals[p];
        den += e;
    }
    #pragma unroll
    for (int off = 32; off >= 1; off >>= 1) {
        num += __shfl_xor(num, off, 64);
        den += __shfl_xor(den, off, 64);
    }
    if (lane == 0) { rednum[wid] = num; redden[wid] = den; }
    __syncthreads();
    if (tid == 0) {
        float nn = rednum[0] + rednum[1] + rednum[2] + rednum[3];
        float dd = redden[0] + redden[1] + redden[2] + redden[3];
        out[b] = nn / dd;
    }
}

extern "C" void kernel_launch(void* const* d_in, const int* in_sizes, int n_in,
                              void* d_out, int out_size, void* d_ws, size_t ws_size,
                              hipStream_t stream) {
    const float* x  = (const float*)d_in[0];
    const float* W1 = (const float*)d_in[1];
    const float* b1 = (const float*)d_in[2];
    const float* Ws = (const float*)d_in[3];
    const float* bs = (const float*)d_in[4];
    float* out = (float*)d_out;
    const int B = in_sizes[0] / (F * D);  // 2048
    afm_kernel<<<B, 256, 0, stream>>>(x, W1, b1, Ws, bs, out);
}

// Round 4
// 84.449 us; speedup vs baseline: 1.1866x; 1.0061x over previous
//
#include <hip/hip_runtime.h>

// AttentionBasedPooling: B=2048, F=32 (P=496 pairs), D=64, H=64.
// afm[b] = sum_p attn[b,p] * dot(x_i,x_j); attn = softmax_p of
// scores[p] = relu((x_i*x_j)@W1 + b1)@Ws + bs.
// One block/batch. FP16 datapath, mfma_f32_16x16x32_f16.
// s_p via extra MFMA against an all-ones column-0 B fragment.
// 2-tile unroll per wave iteration: overlaps the DS-latency + DPP-epilogue
// chains of two independent tiles (kernel was latency-bound at 1 tile).
// Tile 31 is a dummy (pairs >= 496 -> scores[496..511], never read).

#define F 32
#define D 64
#define H 64
#define P 496
#define NT 4
#define MT 32   // padded; tile 31 is dummy
#define RB 72   // f16 per xs row: 64 + 8 pad -> 144 B row stride

typedef __attribute__((ext_vector_type(8))) _Float16 f16x8;
typedef __attribute__((ext_vector_type(2))) _Float16 f16x2;
typedef __attribute__((ext_vector_type(4))) float f32x4;

// VALU-pipe butterfly add over the 16-lane row (no DS traffic)
#define DPP_ADD(v, ctrl) ((v) + __int_as_float(__builtin_amdgcn_update_dpp( \
        0, __float_as_int(v), (ctrl), 0xF, 0xF, true)))

__global__ __launch_bounds__(256, 4) void afm_kernel(
    const float* __restrict__ x, const float* __restrict__ W1,
    const float* __restrict__ b1, const float* __restrict__ Ws,
    const float* __restrict__ bs, float* __restrict__ out)
{
    __shared__ _Float16 xs[F * RB];       // f16 x-tile
    __shared__ int   pairtab[512];        // (i_off<<16)|j_off byte offsets
    __shared__ float scores[512];
    __shared__ float svals[512];
    __shared__ float2 bw[H];              // {b1[n], Ws[n]}
    __shared__ float redmax[4], rednum[4], redden[4];

    const int tid  = threadIdx.x;
    const int b    = blockIdx.x;
    const int lane = tid & 63;
    const int wid  = tid >> 6;
    const int l15  = lane & 15;
    const int quad = lane >> 4;

    // ---- stage x[b] -> f16 LDS (coalesced float4 reads) ----
    const float4* xb4 = (const float4*)(x + (size_t)b * (F * D));
    for (int v = tid; v < (F * D) / 4; v += 256) {
        float4 w = xb4[v];
        int row = v >> 4, col = (v & 15) * 4;
        f16x2 lo = { (_Float16)w.x, (_Float16)w.y };
        f16x2 hi = { (_Float16)w.z, (_Float16)w.w };
        *(f16x2*)&xs[row * RB + col]     = lo;
        *(f16x2*)&xs[row * RB + col + 2] = hi;
    }
    if (tid < H) bw[tid] = make_float2(b1[tid], Ws[tid]);
    // pair table via closed form: i = floor((63 - sqrt(3969-8p))/2), exact
    // at boundaries (perfect-square discriminant); one-step correction.
    for (int p = tid; p < 512; p += 256) {
        int i, j;
        if (p < P) {
            i = (int)((63.0f - __builtin_sqrtf((float)(3969 - 8 * p))) * 0.5f);
            if (i * (63 - i) / 2 > p) --i;
            if ((i + 1) * (62 - i) / 2 <= p) ++i;
            j = i + 1 + (p - i * (63 - i) / 2);
        } else { i = 0; j = 0; }  // dummy pairs for tile 31
        pairtab[p] = (i * RB * 2) << 16 | (j * RB * 2);
    }
    const float bsv = bs[0];
    __syncthreads();

    // ---- W1 as B-fragments in registers (B[k=quad*8+j+32ks][n=nt*16+l15]) ----
    f16x8 bfrag[NT][2];
    #pragma unroll
    for (int nt = 0; nt < NT; ++nt)
        #pragma unroll
        for (int ks = 0; ks < 2; ++ks)
            #pragma unroll
            for (int j8 = 0; j8 < 8; ++j8) {
                int k = quad * 8 + j8 + ks * 32;
                bfrag[nt][ks][j8] = (_Float16)W1[k * H + nt * 16 + l15];
            }
    // all-ones column-0 B fragment: C[:,0] = row-sum of A = s_p
    const _Float16 onev = (l15 == 0) ? (_Float16)1.0f : (_Float16)0.0f;
    const f16x8 onesf = {onev, onev, onev, onev, onev, onev, onev, onev};

    float bb[NT], ww[NT];
    #pragma unroll
    for (int nt = 0; nt < NT; ++nt) {
        float2 t = bw[nt * 16 + l15];
        bb[nt] = t.x; ww[nt] = t.y;
    }

    const char* xsb = (const char*)xs;
    const int qb = quad << 4;

    // ---- per-wave: 4 iterations x 2 independent tiles of 16 pairs ----
    for (int t = wid; t < MT; t += 8) {
        int p0[2]; p0[0] = t * 16; p0[1] = (t + 4) * 16;
        f16x8 A0[2], A1[2];
        f32x4 acc[2][NT], accs[2];

        #pragma unroll
        for (int u = 0; u < 2; ++u) {
            const int pk = pairtab[p0[u] + l15];
            const int io = ((unsigned)pk) >> 16;
            const int jo = pk & 0xFFFF;
            f16x8 xi0 = *(const f16x8*)(xsb + io + qb);
            f16x8 xj0 = *(const f16x8*)(xsb + jo + qb);
            f16x8 xi1 = *(const f16x8*)(xsb + io + 64 + qb);
            f16x8 xj1 = *(const f16x8*)(xsb + jo + 64 + qb);
            A0[u] = xi0 * xj0;
            A1[u] = xi1 * xj1;
        }

        #pragma unroll
        for (int u = 0; u < 2; ++u) {
            #pragma unroll
            for (int nt = 0; nt < NT; ++nt) { f32x4 z = {0.f,0.f,0.f,0.f}; acc[u][nt] = z; }
            f32x4 z = {0.f,0.f,0.f,0.f}; accs[u] = z;
            #pragma unroll
            for (int nt = 0; nt < NT; ++nt)
                acc[u][nt] = __builtin_amdgcn_mfma_f32_16x16x32_f16(A0[u], bfrag[nt][0], acc[u][nt], 0, 0, 0);
            accs[u] = __builtin_amdgcn_mfma_f32_16x16x32_f16(A0[u], onesf, accs[u], 0, 0, 0);
            #pragma unroll
            for (int nt = 0; nt < NT; ++nt)
                acc[u][nt] = __builtin_amdgcn_mfma_f32_16x16x32_f16(A1[u], bfrag[nt][1], acc[u][nt], 0, 0, 0);
            accs[u] = __builtin_amdgcn_mfma_f32_16x16x32_f16(A1[u], onesf, accs[u], 0, 0, 0);
        }

        // score[m] = sum_n relu(C[m][n]+b1[n])*Ws[n]; C: row=quad*4+reg, col=nt*16+l15
        #pragma unroll
        for (int u = 0; u < 2; ++u) {
            float spr[4];
            #pragma unroll
            for (int reg = 0; reg < 4; ++reg) {
                float s = 0.f;
                #pragma unroll
                for (int nt = 0; nt < NT; ++nt) {
                    float v = acc[u][nt][reg] + bb[nt];
                    v = v > 0.f ? v : 0.f;
                    s += v * ww[nt];
                }
                s = DPP_ADD(s, 0xB1);   // xor1
                s = DPP_ADD(s, 0x4E);   // xor2
                s = DPP_ADD(s, 0x141);  // row_half_mirror
                s = DPP_ADD(s, 0x140);  // row_mirror
                spr[reg] = s;
            }
            if (l15 == 0) {
                *(float4*)&svals[p0[u] + quad * 4] =
                    make_float4(accs[u][0], accs[u][1], accs[u][2], accs[u][3]);
                *(float4*)&scores[p0[u] + quad * 4] =
                    make_float4(spr[0] + bsv, spr[1] + bsv, spr[2] + bsv, spr[3] + bsv);
            }
        }
    }
    __syncthreads();

    // ---- softmax over 496 pairs; afm = sum attn*s ----
    float m = -1e30f;
    for (int p = tid; p < P; p += 256) m = fmaxf(m, scores[p]);
    #pragma unroll
    for (int off = 32; off >= 1; off >>= 1) m = fmaxf(m, __shfl_xor(m, off, 64));
    if (lane == 0) redmax[wid] = m;
    __syncthreads();
    m = fmaxf(fmaxf(redmax[0], redmax[1]), fmaxf(redmax[2], redmax[3]));

    float num = 0.f, den = 0.f;
    for (int p = tid; p < P; p += 256) {
        float e = __expf(scores[p] - m);
        num += e * svals[p];
        den += e;
    }
    #pragma unroll
    for (int off = 32; off >= 1; off >>= 1) {
        num += __shfl_xor(num, off, 64);
        den += __shfl_xor(den, off, 64);
    }
    if (lane == 0) { rednum[wid] = num; redden[wid] = den; }
    __syncthreads();
    if (tid == 0) {
        float nn = rednum[0] + rednum[1] + rednum[2] + rednum[3];
        float dd = redden[0] + redden[1] + redden[2] + redden[3];
        out[b] = nn / dd;
    }
}

extern "C" void kernel_launch(void* const* d_in, const int* in_sizes, int n_in,
                              void* d_out, int out_size, void* d_ws, size_t ws_size,
                              hipStream_t stream) {
    const float* x  = (const float*)d_in[0];
    const float* W1 = (const float*)d_in[1];
    const float* b1 = (const float*)d_in[2];
    const float* Ws = (const float*)d_in[3];
    const float* bs = (const float*)d_in[4];
    float* out = (float*)d_out;
    const int B = in_sizes[0] / (F * D);  // 2048
    afm_kernel<<<B, 256, 0, stream>>>(x, W1, b1, Ws, bs, out);
}

// Round 5
// 83.906 us; speedup vs baseline: 1.1943x; 1.0065x over previous
//
#include <hip/hip_runtime.h>

// AttentionBasedPooling: B=2048, F=32 (P=496 pairs), D=64, H=64.
// afm[b] = sum_p attn[b,p] * dot(x_i,x_j); attn = softmax_p of
// scores[p] = relu((x_i*x_j)@W1 + b1)@Ws + bs.
// One block/batch. FP16 datapath, mfma_f32_16x16x32_f16 with SWAPPED
// operands: D = W1^T-frag (A) x cross-frag (B) = h^T. A-layout
// [row=l15][k=quad*8+j] and B-layout [k=quad*8+j][col=l15] share the same
// lane mapping, so both fragment builds are unchanged from the verified
// version; only the epilogue changes: each lane reduces its 16 in-lane
// h values (48 VALU) + 2 shfl_xor across quads. No DPP chains.
// s_p via ones-row A fragment -> lands at row0 (quad0, reg0).

#define F 32
#define D 64
#define H 64
#define P 496
#define NT 4
#define MT 32   // padded; tile 31 is dummy (writes scores[496..511], never read)
#define RB 72   // f16 per xs row: 64 + 8 pad -> 144 B row stride

typedef __attribute__((ext_vector_type(8))) _Float16 f16x8;
typedef __attribute__((ext_vector_type(2))) _Float16 f16x2;
typedef __attribute__((ext_vector_type(4))) float f32x4;

__global__ __launch_bounds__(256, 4) void afm_kernel(
    const float* __restrict__ x, const float* __restrict__ W1,
    const float* __restrict__ b1, const float* __restrict__ Ws,
    const float* __restrict__ bs, float* __restrict__ out)
{
    __shared__ _Float16 xs[F * RB];       // f16 x-tile
    __shared__ int   pairtab[512];        // (i_off<<16)|j_off byte offsets
    __shared__ float scores[512];
    __shared__ float svals[512];
    __shared__ float redmax[4], rednum[4], redden[4];

    const int tid  = threadIdx.x;
    const int b    = blockIdx.x;
    const int lane = tid & 63;
    const int wid  = tid >> 6;
    const int l15  = lane & 15;
    const int quad = lane >> 4;

    // ---- stage x[b] -> f16 LDS (coalesced float4 reads) ----
    const float4* xb4 = (const float4*)(x + (size_t)b * (F * D));
    for (int v = tid; v < (F * D) / 4; v += 256) {
        float4 w = xb4[v];
        int row = v >> 4, col = (v & 15) * 4;
        f16x2 lo = { (_Float16)w.x, (_Float16)w.y };
        f16x2 hi = { (_Float16)w.z, (_Float16)w.w };
        *(f16x2*)&xs[row * RB + col]     = lo;
        *(f16x2*)&xs[row * RB + col + 2] = hi;
    }
    // pair table, closed form (exact at boundaries; one-step correction)
    for (int p = tid; p < 512; p += 256) {
        int i, j;
        if (p < P) {
            i = (int)((63.0f - __builtin_sqrtf((float)(3969 - 8 * p))) * 0.5f);
            if (i * (63 - i) / 2 > p) --i;
            if ((i + 1) * (62 - i) / 2 <= p) ++i;
            j = i + 1 + (p - i * (63 - i) / 2);
        } else { i = 0; j = 0; }
        pairtab[p] = (i * RB * 2) << 16 | (j * RB * 2);
    }
    const float bsv = bs[0];

    // ---- W1^T as A-fragments (same indexing as the verified B-frag build):
    // frag[nt][ks][j8] = W1[(quad*8+j8+32ks)*H + nt*16+l15]
    f16x8 wfrag[NT][2];
    #pragma unroll
    for (int nt = 0; nt < NT; ++nt)
        #pragma unroll
        for (int ks = 0; ks < 2; ++ks)
            #pragma unroll
            for (int j8 = 0; j8 < 8; ++j8) {
                int k = quad * 8 + j8 + ks * 32;
                wfrag[nt][ks][j8] = (_Float16)W1[k * H + nt * 16 + l15];
            }
    // ones-row A fragment: A[0][k]=1 -> D[0][m] = sum_k B[k][m] = s_m
    const _Float16 onev = (l15 == 0) ? (_Float16)1.0f : (_Float16)0.0f;
    const f16x8 onesf = {onev, onev, onev, onev, onev, onev, onev, onev};

    // per-lane b1/Ws for n = nt*16 + quad*4 + reg (L1-resident, 512 B each)
    float breg[16], wreg[16];
    #pragma unroll
    for (int nt = 0; nt < NT; ++nt)
        #pragma unroll
        for (int reg = 0; reg < 4; ++reg) {
            int n = nt * 16 + quad * 4 + reg;
            breg[nt * 4 + reg] = b1[n];
            wreg[nt * 4 + reg] = Ws[n];
        }
    __syncthreads();

    const char* xsb = (const char*)xs;
    const int qb = quad << 4;

    // ---- per-wave m-tiles of 16 pairs ----
    for (int t = wid; t < MT; t += 4) {
        const int p0 = t * 16;
        const int pk = pairtab[p0 + l15];
        const int io = ((unsigned)pk) >> 16;
        const int jo = pk & 0xFFFF;

        f16x8 xi0 = *(const f16x8*)(xsb + io + qb);        // k 0..31
        f16x8 xj0 = *(const f16x8*)(xsb + jo + qb);
        f16x8 xi1 = *(const f16x8*)(xsb + io + 64 + qb);   // k 32..63
        f16x8 xj1 = *(const f16x8*)(xsb + jo + 64 + qb);

        f16x8 A0 = xi0 * xj0;   // 4x v_pk_mul_f16
        f16x8 A1 = xi1 * xj1;

        f32x4 acc[NT];
        #pragma unroll
        for (int nt = 0; nt < NT; ++nt) { f32x4 z = {0.f,0.f,0.f,0.f}; acc[nt] = z; }
        f32x4 accs = {0.f, 0.f, 0.f, 0.f};

        // D = W1^T x cross -> h^T : row = n' = quad*4+reg, col = m = l15
        #pragma unroll
        for (int nt = 0; nt < NT; ++nt)
            acc[nt] = __builtin_amdgcn_mfma_f32_16x16x32_f16(wfrag[nt][0], A0, acc[nt], 0, 0, 0);
        accs = __builtin_amdgcn_mfma_f32_16x16x32_f16(onesf, A0, accs, 0, 0, 0);
        #pragma unroll
        for (int nt = 0; nt < NT; ++nt)
            acc[nt] = __builtin_amdgcn_mfma_f32_16x16x32_f16(wfrag[nt][1], A1, acc[nt], 0, 0, 0);
        accs = __builtin_amdgcn_mfma_f32_16x16x32_f16(onesf, A1, accs, 0, 0, 0);

        // in-lane partial: sum over n = nt*16+quad*4+reg of relu(h+b1)*Ws
        float s = 0.f;
        #pragma unroll
        for (int nt = 0; nt < NT; ++nt)
            #pragma unroll
            for (int reg = 0; reg < 4; ++reg) {
                float v = acc[nt][reg] + breg[nt * 4 + reg];
                v = v > 0.f ? v : 0.f;
                s = fmaf(v, wreg[nt * 4 + reg], s);
            }
        // reduce across the 4 quads (same m = l15)
        s += __shfl_xor(s, 16, 64);
        s += __shfl_xor(s, 32, 64);
        if (quad == 0) {
            scores[p0 + l15] = s + bsv;
            svals[p0 + l15]  = accs[0];   // row 0 of ones-MFMA = s_m
        }
    }
    __syncthreads();

    // ---- softmax over 496 pairs; afm = sum attn*s ----
    float m = -1e30f;
    for (int p = tid; p < P; p += 256) m = fmaxf(m, scores[p]);
    #pragma unroll
    for (int off = 32; off >= 1; off >>= 1) m = fmaxf(m, __shfl_xor(m, off, 64));
    if (lane == 0) redmax[wid] = m;
    __syncthreads();
    m = fmaxf(fmaxf(redmax[0], redmax[1]), fmaxf(redmax[2], redmax[3]));

    float num = 0.f, den = 0.f;
    for (int p = tid; p < P; p += 256) {
        float e = __expf(scores[p] - m);
        num += e * svals[p];
        den += e;
    }
    #pragma unroll
    for (int off = 32; off >= 1; off >>= 1) {
        num += __shfl_xor(num, off, 64);
        den += __shfl_xor(den, off, 64);
    }
    if (lane == 0) { rednum[wid] = num; redden[wid] = den; }
    __syncthreads();
    if (tid == 0) {
        float nn = rednum[0] + rednum[1] + rednum[2] + rednum[3];
        float dd = redden[0] + redden[1] + redden[2] + redden[3];
        out[b] = nn / dd;
    }
}

extern "C" void kernel_launch(void* const* d_in, const int* in_sizes, int n_in,
                              void* d_out, int out_size, void* d_ws, size_t ws_size,
                              hipStream_t stream) {
    const float* x  = (const float*)d_in[0];
    const float* W1 = (const float*)d_in[1];
    const float* b1 = (const float*)d_in[2];
    const float* Ws = (const float*)d_in[3];
    const float* bs = (const float*)d_in[4];
    float* out = (float*)d_out;
    const int B = in_sizes[0] / (F * D);  // 2048
    afm_kernel<<<B, 256, 0, stream>>>(x, W1, b1, Ws, bs, out);
}